// Round 3
// baseline (182.724 us; speedup 1.0000x reference)
//
#include <hip/hip_runtime.h>
#include <stdint.h>

#define NTOK 4096
#define CDIM 512
#define HEADS 8
#define DHEAD 64
#define PHEAD (NTOK * DHEAD)          // 262144 elems per head per tensor

typedef __bf16 bf16x8 __attribute__((ext_vector_type(8)));
typedef __bf16 bf16x4 __attribute__((ext_vector_type(4)));
typedef short short4v __attribute__((ext_vector_type(4)));
typedef float f32x4 __attribute__((ext_vector_type(4)));

__device__ __forceinline__ unsigned short f2bf(float f) {
    unsigned int u = __builtin_bit_cast(unsigned int, f);
    unsigned int r = (u + 0x7FFFu + ((u >> 16) & 1u)) >> 16;
    return (unsigned short)r;
}
__device__ __forceinline__ unsigned short bfbits(float f) {
    return __builtin_bit_cast(unsigned short, (__bf16)f);   // hw v_cvt on gfx950
}

__device__ __forceinline__ f32x4 mfma32(bf16x8 a, bf16x8 b, f32x4 c) {
    return __builtin_amdgcn_mfma_f32_16x16x32_bf16(a, b, c, 0, 0, 0);
}
__device__ __forceinline__ f32x4 mfma16(short4v a, short4v b, f32x4 c) {
    return __builtin_amdgcn_mfma_f32_16x16x16bf16_1k(a, b, c, 0, 0, 0);
}

// ---------------- fused fp32 -> bf16 casts ----------------
__global__ void cast3_k(const float* __restrict__ x, const float* __restrict__ wq,
                        const float* __restrict__ wp,
                        unsigned short* __restrict__ xb, unsigned short* __restrict__ wqb,
                        unsigned short* __restrict__ wpb) {
    const int b = blockIdx.x;
    const float* src; unsigned short* dst; int base;
    if (b < 2048)      { src = x;  dst = xb;  base = b * 1024; }
    else if (b < 2816) { src = wq; dst = wqb; base = (b - 2048) * 1024; }
    else               { src = wp; dst = wpb; base = (b - 2816) * 1024; }
    const int i = base + threadIdx.x * 4;
    const float4 v = *(const float4*)(src + i);
    ushort4 o;
    o.x = bfbits(v.x); o.y = bfbits(v.y); o.z = bfbits(v.z); o.w = bfbits(v.w);
    *(ushort4*)(dst + i) = o;
}

// ---------------- bf16 GEMM, C = A * B^T (+bias), 128x128 tile ----------------
// MODE 0: QKV -> LDS-transposed epilogue, coalesced 16B stores into frag layouts
// MODE 1: proj -> fp32 store to c_out (row-major M x Nn)
template<int MODE>
__global__ __launch_bounds__(256) void gemm_bt(
    const unsigned short* __restrict__ A,
    const unsigned short* __restrict__ Bm,
    const float* __restrict__ bias,
    const float* __restrict__ scale_p,
    unsigned short* __restrict__ qkv_out,
    float* __restrict__ c_out,
    int M, int Nn, int K)
{
    __shared__ __align__(16) unsigned short smem[128 * 136];   // 34816 B
    unsigned short* lA = smem;              // 128*32 elems
    unsigned short* lB = smem + 128 * 32;   // 128*32 elems

    const int tid = threadIdx.x;
    const int mBase = blockIdx.y * 128, nBase = blockIdx.x * 128;
    const int lane = tid & 63, w = tid >> 6;
    const int l16 = lane & 15, quad = lane >> 4;
    const int wr = (w >> 1) * 64, wc = (w & 1) * 64;

    f32x4 acc[4][4] = {};

    for (int kt = 0; kt < K; kt += 32) {
        __syncthreads();
#pragma unroll
        for (int i = 0; i < 2; ++i) {
            const int c = tid + i * 256;
            const int fe = c * 8;
            const int row = fe >> 5, col = fe & 31;
            *(uint4*)&lA[fe] = *(const uint4*)&A[(size_t)(mBase + row) * K + kt + col];
            *(uint4*)&lB[fe] = *(const uint4*)&Bm[(size_t)(nBase + row) * K + kt + col];
        }
        __syncthreads();

        bf16x8 af[4], bfr[4];
#pragma unroll
        for (int i = 0; i < 4; ++i)
            af[i] = *(const bf16x8*)&lA[(wr + i * 16 + l16) * 32 + quad * 8];
#pragma unroll
        for (int j = 0; j < 4; ++j)
            bfr[j] = *(const bf16x8*)&lB[(wc + j * 16 + l16) * 32 + quad * 8];
#pragma unroll
        for (int i = 0; i < 4; ++i)
#pragma unroll
            for (int j = 0; j < 4; ++j)
                acc[i][j] = mfma32(af[i], bfr[j], acc[i][j]);
    }

    if (MODE == 1) {
#pragma unroll
        for (int i = 0; i < 4; ++i)
#pragma unroll
            for (int j = 0; j < 4; ++j)
#pragma unroll
                for (int r = 0; r < 4; ++r) {
                    const int grow = mBase + wr + i * 16 + quad * 4 + r;
                    const int gcol = nBase + wc + j * 16 + l16;
                    c_out[(size_t)grow * Nn + gcol] = acc[i][j][r] + bias[gcol];
                }
    } else {
        const int three = nBase >> 9;               // block-uniform: 0 q, 1 k, 2 v
        const float scl = scale_p[0] * 1.44269504f; // fold log2(e) for exp2 softmax
        const float mul = (three == 0) ? scl : 1.0f;

        __syncthreads();   // frag reads of lA/lB done before overwrite
#pragma unroll
        for (int i = 0; i < 4; ++i)
#pragma unroll
            for (int j = 0; j < 4; ++j)
#pragma unroll
                for (int r = 0; r < 4; ++r) {
                    const int rl = wr + i * 16 + quad * 4 + r;
                    const int cl = wc + j * 16 + l16;
                    const float v = (acc[i][j][r] + bias[nBase + cl]) * mul;
                    smem[rl * 136 + cl] = bfbits(v);
                }
        __syncthreads();

        const size_t base3 = (size_t)three * (PHEAD * HEADS);
        if (three < 2) {
            // 16B chunk = 8 contiguous head-dims of one token row
#pragma unroll
            for (int pass = 0; pass < 8; ++pass) {
                const int idx = pass * 256 + tid;
                const int rl16 = idx & 15, qc = (idx >> 4) & 7;
                const int hsel = (idx >> 7) & 1, t16l = idx >> 8;
                const uint4 d = *(const uint4*)&smem[(t16l * 16 + rl16) * 136 + hsel * 64 + qc * 8];
                const int hh = ((nBase >> 6) + hsel) & 7;
                const int t16 = (mBase >> 4) + t16l;
                const size_t dst = base3 + (size_t)hh * PHEAD +
                    (size_t)(((t16 * 2 + (qc >> 2)) * 64 + (qc & 3) * 16 + rl16) * 8);
                *(uint4*)&qkv_out[dst] = d;
            }
        } else {
            // V^T frag: 16B chunk = 2 head-dims x 4 keys
#pragma unroll
            for (int pass = 0; pass < 8; ++pass) {
                const int idx = pass * 256 + tid;
                const int d0 = (idx & 7) * 2, kq = (idx >> 3) & 3;
                const int dt = (idx >> 5) & 3, k16l = (idx >> 7) & 7, hsel = (idx >> 10) & 1;
                const int colb = hsel * 64 + dt * 16 + d0;
                unsigned int u[4];
#pragma unroll
                for (int e = 0; e < 4; ++e)
                    u[e] = *(const unsigned int*)&smem[(k16l * 16 + kq * 4 + e) * 136 + colb];
                uint4 o;
                o.x = (u[0] & 0xffffu) | (u[1] << 16);
                o.y = (u[2] & 0xffffu) | (u[3] << 16);
                o.z = (u[0] >> 16)     | (u[1] & 0xffff0000u);
                o.w = (u[2] >> 16)     | (u[3] & 0xffff0000u);
                const int hh = ((nBase >> 6) + hsel) & 7;
                const int k16 = (mBase >> 4) + k16l;
                const size_t dst = base3 + (size_t)hh * PHEAD +
                    (size_t)((((k16 * 4 + dt) * 64) + kq * 16 + d0) * 4);
                *(uint4*)&qkv_out[dst] = o;
            }
        }
    }
}

// ---------------- flash attention: LDS/barrier-free main loop, SGPR addressing ----------------
__global__ __launch_bounds__(256) void flash2_k(
    const unsigned short* __restrict__ qf,
    const unsigned short* __restrict__ kf,
    const unsigned short* __restrict__ vf,
    unsigned short* __restrict__ attn_out)   // [N][C] bf16
{
    __shared__ float ldsO[4][32][68];
    __shared__ float sml[2][4][32];

    const int tid = threadIdx.x;
    const int lane = tid & 63;
    const int w = __builtin_amdgcn_readfirstlane(tid >> 6);   // wave-uniform -> SGPR
    const int l16 = lane & 15, quad = lane >> 4;
    const int h = blockIdx.y, qb = blockIdx.x;

    const unsigned short* qh = qf + (size_t)h * PHEAD;
    const unsigned short* kb = kf + (size_t)h * PHEAD + w * 4096;
    const unsigned short* vb = vf + (size_t)h * PHEAD + w * 4096;

    bf16x8 qfr[2][2];
#pragma unroll
    for (int qt = 0; qt < 2; ++qt)
#pragma unroll
        for (int ks = 0; ks < 2; ++ks)
            qfr[qt][ks] = *(const bf16x8*)&qh[((qb * 2 + qt) * 2 + ks) * 512 + lane * 8];

    f32x4 oacc[4][2] = {};              // [dtile][qtile], O^T: d=quad*4+r, q=l16
    float m[2] = {-3.0e38f, -3.0e38f};
    float l[2] = {0.f, 0.f};

    for (int it = 0; it < 16; ++it, kb += 16384, vb += 16384) {
        f32x4 s[4][2];
#pragma unroll
        for (int kt = 0; kt < 4; ++kt) {
            const bf16x8 k0 = *(const bf16x8*)&kb[kt * 1024 + lane * 8];
            const bf16x8 k1 = *(const bf16x8*)&kb[kt * 1024 + 512 + lane * 8];
#pragma unroll
            for (int qt = 0; qt < 2; ++qt) {
                f32x4 a = {};
                a = mfma32(k0, qfr[qt][0], a);
                a = mfma32(k1, qfr[qt][1], a);
                s[kt][qt] = a;
            }
        }

        short4v pf[4][2];
        float alpha[2];
#pragma unroll
        for (int qt = 0; qt < 2; ++qt) {
            float mx = s[0][qt][0];
#pragma unroll
            for (int kt = 0; kt < 4; ++kt)
#pragma unroll
                for (int r = 0; r < 4; ++r) mx = fmaxf(mx, s[kt][qt][r]);
            mx = fmaxf(mx, __shfl_xor(mx, 16, 64));
            mx = fmaxf(mx, __shfl_xor(mx, 32, 64));
            const float mn = fmaxf(m[qt], mx);
            alpha[qt] = __builtin_amdgcn_exp2f(m[qt] - mn);
            m[qt] = mn;
            float ps = 0.f;
#pragma unroll
            for (int kt = 0; kt < 4; ++kt) {
                bf16x4 pb;
#pragma unroll
                for (int r = 0; r < 4; ++r) {
                    const float p = __builtin_amdgcn_exp2f(s[kt][qt][r] - mn);
                    ps += p;
                    pb[r] = (__bf16)p;          // hw packed cvt on gfx950
                }
                pf[kt][qt] = __builtin_bit_cast(short4v, pb);
            }
            ps += __shfl_xor(ps, 16, 64);
            ps += __shfl_xor(ps, 32, 64);
            l[qt] = l[qt] * alpha[qt] + ps;
#pragma unroll
            for (int dt = 0; dt < 4; ++dt) oacc[dt][qt] *= alpha[qt];
        }

#pragma unroll
        for (int kt = 0; kt < 4; ++kt) {
#pragma unroll
            for (int dt = 0; dt < 4; ++dt) {
                const short4v vfr = *(const short4v*)&vb[kt * 1024 + dt * 256 + lane * 4];
#pragma unroll
                for (int qt = 0; qt < 2; ++qt)
                    oacc[dt][qt] = mfma16(vfr, pf[kt][qt], oacc[dt][qt]);
            }
        }
    }

    // ---- 4-way wave merge ----
    if (quad == 0) {
#pragma unroll
        for (int qt = 0; qt < 2; ++qt) {
            sml[0][w][qt * 16 + l16] = m[qt];
            sml[1][w][qt * 16 + l16] = l[qt];
        }
    }
    __syncthreads();
#pragma unroll
    for (int qt = 0; qt < 2; ++qt) {
        const int q = qt * 16 + l16;
        const float M = fmaxf(fmaxf(sml[0][0][q], sml[0][1][q]),
                              fmaxf(sml[0][2][q], sml[0][3][q]));
        const float wt = __builtin_amdgcn_exp2f(m[qt] - M);
#pragma unroll
        for (int dt = 0; dt < 4; ++dt) {
            const f32x4 v = oacc[dt][qt] * wt;
            *(f32x4*)&ldsO[w][q][dt * 16 + quad * 4] = v;
        }
    }
    __syncthreads();
    {
        const int q = tid >> 3, dz = (tid & 7) * 8;
        const float M = fmaxf(fmaxf(sml[0][0][q], sml[0][1][q]),
                              fmaxf(sml[0][2][q], sml[0][3][q]));
        float L = 0.f;
#pragma unroll
        for (int ww = 0; ww < 4; ++ww)
            L += sml[1][ww][q] * __builtin_amdgcn_exp2f(sml[0][ww][q] - M);
        const float inv = 1.f / L;
        unsigned short o8[8];
#pragma unroll
        for (int i = 0; i < 8; ++i) {
            const float v = ldsO[0][q][dz + i] + ldsO[1][q][dz + i] +
                            ldsO[2][q][dz + i] + ldsO[3][q][dz + i];
            o8[i] = bfbits(v * inv);
        }
        *(uint4*)&attn_out[(size_t)(qb * 32 + q) * CDIM + h * DHEAD + dz] = *(uint4*)o8;
    }
}

extern "C" void kernel_launch(void* const* d_in, const int* in_sizes, int n_in,
                              void* d_out, int out_size, void* d_ws, size_t ws_size,
                              hipStream_t stream) {
    const float* x       = (const float*)d_in[0];
    const float* scale_p = (const float*)d_in[3];
    const float* Wqkv    = (const float*)d_in[4];
    const float* bqkv    = (const float*)d_in[5];
    const float* Wproj   = (const float*)d_in[6];
    const float* bproj   = (const float*)d_in[7];
    float* out = (float*)d_out;

    char* ws = (char*)d_ws;
    const size_t OFF_XB    = 0;                       // 4096*512 bf16   = 4 MB
    const size_t OFF_WQKV  = OFF_XB + 4194304;        // 1536*512 bf16   = 1.5 MB
    const size_t OFF_WPROJ = OFF_WQKV + 1572864;      // 512*512 bf16    = 0.5 MB
    const size_t OFF_QKV   = OFF_WPROJ + 524288;      // 3*4096*512 bf16 = 12 MB
    const size_t OFF_ATTN  = OFF_QKV + 12582912;      // 4096*512 bf16   = 4 MB
    const size_t NEEDED    = OFF_ATTN + 4194304;
    if (ws_size < NEEDED) return;

    unsigned short* xb     = (unsigned short*)(ws + OFF_XB);
    unsigned short* wqkvb  = (unsigned short*)(ws + OFF_WQKV);
    unsigned short* wprojb = (unsigned short*)(ws + OFF_WPROJ);
    unsigned short* qkvb   = (unsigned short*)(ws + OFF_QKV);
    unsigned short* attnb  = (unsigned short*)(ws + OFF_ATTN);

    cast3_k<<<3072, 256, 0, stream>>>(x, Wqkv, Wproj, xb, wqkvb, wprojb);

    gemm_bt<0><<<dim3(12, 32), 256, 0, stream>>>(xb, wqkvb, bqkv, scale_p,
                                                 qkvb, nullptr, NTOK, 3 * CDIM, CDIM);

    const unsigned short* qfr = qkvb;
    const unsigned short* kfr = qkvb + (size_t)PHEAD * HEADS;
    const unsigned short* vfr = qkvb + (size_t)2 * PHEAD * HEADS;
    flash2_k<<<dim3(128, 8), 256, 0, stream>>>(qfr, kfr, vfr, attnb);

    gemm_bt<1><<<dim3(4, 32), 256, 0, stream>>>(attnb, wprojb, bproj, nullptr,
                                                nullptr, out, NTOK, CDIM, CDIM);
}

// Round 4
// 172.306 us; speedup vs baseline: 1.0605x; 1.0605x over previous
//
#include <hip/hip_runtime.h>
#include <stdint.h>

#define NTOK 4096
#define CDIM 512
#define HEADS 8
#define DHEAD 64
#define PHEAD (NTOK * DHEAD)          // 262144 elems per head per tensor

typedef __bf16 bf16x8 __attribute__((ext_vector_type(8)));
typedef float f32x4 __attribute__((ext_vector_type(4)));

__device__ __forceinline__ unsigned short bfbits(float f) {
    return __builtin_bit_cast(unsigned short, (__bf16)f);   // hw v_cvt on gfx950
}

__device__ __forceinline__ f32x4 mfma32(bf16x8 a, bf16x8 b, f32x4 c) {
    return __builtin_amdgcn_mfma_f32_16x16x32_bf16(a, b, c, 0, 0, 0);
}

// ---------------- fused fp32 -> bf16 casts ----------------
__global__ void cast3_k(const float* __restrict__ x, const float* __restrict__ wq,
                        const float* __restrict__ wp,
                        unsigned short* __restrict__ xb, unsigned short* __restrict__ wqb,
                        unsigned short* __restrict__ wpb) {
    const int b = blockIdx.x;
    const float* src; unsigned short* dst; int base;
    if (b < 2048)      { src = x;  dst = xb;  base = b * 1024; }
    else if (b < 2816) { src = wq; dst = wqb; base = (b - 2048) * 1024; }
    else               { src = wp; dst = wpb; base = (b - 2816) * 1024; }
    const int i = base + threadIdx.x * 4;
    const float4 v = *(const float4*)(src + i);
    ushort4 o;
    o.x = bfbits(v.x); o.y = bfbits(v.y); o.z = bfbits(v.z); o.w = bfbits(v.w);
    *(ushort4*)(dst + i) = o;
}

// ---------------- bf16 GEMM, C = A * B^T (+bias), 64x128 tile ----------------
// MODE 0: QKV -> LDS-transposed epilogue, coalesced 16B stores into frag layouts
//         (V gets the PV-mfma32 key-permuted fragment layout)
// MODE 1: proj -> fp32 store to c_out (row-major M x Nn)
template<int MODE>
__global__ __launch_bounds__(256) void gemm_bt(
    const unsigned short* __restrict__ A,
    const unsigned short* __restrict__ Bm,
    const float* __restrict__ bias,
    const float* __restrict__ scale_p,
    unsigned short* __restrict__ qkv_out,
    float* __restrict__ c_out,
    int M, int Nn, int K)
{
    __shared__ __align__(16) unsigned short smem[64 * 136];   // 17408 B (K-loop uses 6144 elems)
    unsigned short* lA = smem;              // 64*32 elems
    unsigned short* lB = smem + 64 * 32;    // 128*32 elems

    const int tid = threadIdx.x;
    const int mBase = blockIdx.y * 64, nBase = blockIdx.x * 128;
    const int lane = tid & 63, w = tid >> 6;
    const int l16 = lane & 15, quad = lane >> 4;

    f32x4 acc[4][2] = {};   // wave w owns cols [w*32, w*32+32), all 64 rows

    for (int kt = 0; kt < K; kt += 32) {
        __syncthreads();
        {
            const int fe = tid * 8;                     // A: 2048 elems, 1 pass
            const int row = fe >> 5, col = fe & 31;
            *(uint4*)&lA[fe] = *(const uint4*)&A[(size_t)(mBase + row) * K + kt + col];
        }
#pragma unroll
        for (int i = 0; i < 2; ++i) {                   // B: 4096 elems, 2 passes
            const int fe = (i * 256 + tid) * 8;
            const int row = fe >> 5, col = fe & 31;
            *(uint4*)&lB[fe] = *(const uint4*)&Bm[(size_t)(nBase + row) * K + kt + col];
        }
        __syncthreads();

        bf16x8 af[4], bfr[2];
#pragma unroll
        for (int i = 0; i < 4; ++i)
            af[i] = *(const bf16x8*)&lA[(i * 16 + l16) * 32 + quad * 8];
#pragma unroll
        for (int j = 0; j < 2; ++j)
            bfr[j] = *(const bf16x8*)&lB[(w * 32 + j * 16 + l16) * 32 + quad * 8];
#pragma unroll
        for (int i = 0; i < 4; ++i)
#pragma unroll
            for (int j = 0; j < 2; ++j)
                acc[i][j] = mfma32(af[i], bfr[j], acc[i][j]);
    }

    if (MODE == 1) {
#pragma unroll
        for (int i = 0; i < 4; ++i)
#pragma unroll
            for (int j = 0; j < 2; ++j)
#pragma unroll
                for (int r = 0; r < 4; ++r) {
                    const int grow = mBase + i * 16 + quad * 4 + r;
                    const int gcol = nBase + w * 32 + j * 16 + l16;
                    c_out[(size_t)grow * Nn + gcol] = acc[i][j][r] + bias[gcol];
                }
    } else {
        const int three = nBase >> 9;               // block-uniform: 0 q, 1 k, 2 v
        const float scl = scale_p[0] * 1.44269504f; // fold log2(e) for exp2 softmax
        const float mul = (three == 0) ? scl : 1.0f;

        __syncthreads();   // K-loop frag reads done before overwrite
#pragma unroll
        for (int i = 0; i < 4; ++i)
#pragma unroll
            for (int j = 0; j < 2; ++j)
#pragma unroll
                for (int r = 0; r < 4; ++r) {
                    const int rl = i * 16 + quad * 4 + r;
                    const int cl = w * 32 + j * 16 + l16;
                    const float v = (acc[i][j][r] + bias[nBase + cl]) * mul;
                    smem[rl * 136 + cl] = bfbits(v);
                }
        __syncthreads();

        const size_t base3 = (size_t)three * (PHEAD * HEADS);
        if (three < 2) {
            // Q/K frag layout [h][t16][ks][quad*16+l16][8]; 16B chunk = 8 head-dims of 1 token
#pragma unroll
            for (int pass = 0; pass < 4; ++pass) {
                const int idx = pass * 256 + tid;
                const int rl16 = idx & 15, qc = (idx >> 4) & 7;
                const int hsel = (idx >> 7) & 1, t16l = (idx >> 8) & 3;
                const uint4 d = *(const uint4*)&smem[(t16l * 16 + rl16) * 136 + hsel * 64 + qc * 8];
                const int hh = ((nBase >> 6) + hsel) & 7;
                const int t16 = (mBase >> 4) + t16l;
                const size_t dst = base3 + (size_t)hh * PHEAD +
                    (size_t)(((t16 * 2 + (qc >> 2)) * 64 + (qc & 3) * 16 + rl16) * 8);
                *(uint4*)&qkv_out[dst] = d;
            }
        } else {
            // V frag layout [h][k32][dt][quad*16+l16][8]:
            // elem j = V[key = k32*32 + (j<4 ? quad*4+j : 16+quad*4+j-4)][d = dt*16+l16]
#pragma unroll
            for (int pass = 0; pass < 4; ++pass) {
                const int idx = pass * 256 + tid;
                const int l16t = idx & 15, quadt = (idx >> 4) & 3;
                const int dt = (idx >> 6) & 3, k32l = (idx >> 8) & 1, hsel = (idx >> 9) & 1;
                const int col = hsel * 64 + dt * 16 + l16t;
                unsigned short o8[8];
#pragma unroll
                for (int e = 0; e < 4; ++e) {
                    o8[e]     = smem[(k32l * 32 + quadt * 4 + e) * 136 + col];
                    o8[e + 4] = smem[(k32l * 32 + 16 + quadt * 4 + e) * 136 + col];
                }
                const int hh = ((nBase >> 6) + hsel) & 7;
                const int k32 = (mBase >> 5) + k32l;
                const size_t dst = base3 + (size_t)hh * PHEAD +
                    (size_t)(((k32 * 4 + dt) * 64 + quadt * 16 + l16t) * 8);
                *(uint4*)&qkv_out[dst] = *(uint4*)o8;
            }
        }
    }
}

// ---------------- flash attention v3: 64-query blocks, static-max softmax ----------------
// 4 waves split keys 4-way; main loop has no LDS, no barriers, no cross-lane ops.
// S^T = K Q^T (16x16x32); P = exp2(S^T) lands directly in B-frag layout for
// PV O^T = V^T P^T (16x16x32, V key-permuted); l accumulated by ones-MFMA.
__global__ __launch_bounds__(256, 2) void flash3_k(
    const unsigned short* __restrict__ qf,
    const unsigned short* __restrict__ kf,
    const unsigned short* __restrict__ vf,
    unsigned short* __restrict__ attn_out)   // [N][C] bf16
{
    __shared__ float ldsO[4][32][68];   // [wave][q(half)][d]
    __shared__ float sml[4][64];        // per-wave l sums

    const int tid = threadIdx.x;
    const int lane = tid & 63;
    const int w = __builtin_amdgcn_readfirstlane(tid >> 6);
    const int l16 = lane & 15, quad = lane >> 4;
    const int h = blockIdx.y, qb = blockIdx.x;

    const unsigned short* qh = qf + (size_t)h * PHEAD;
    const unsigned short* kb = kf + (size_t)h * PHEAD + w * 4096;
    const unsigned short* vb = vf + (size_t)h * PHEAD + w * 4096;

    bf16x8 qfr[4][2];
#pragma unroll
    for (int qt = 0; qt < 4; ++qt)
#pragma unroll
        for (int ks = 0; ks < 2; ++ks)
            qfr[qt][ks] = *(const bf16x8*)&qh[((qb * 4 + qt) * 2 + ks) * 512 + lane * 8];

    bf16x8 ones;
#pragma unroll
    for (int j = 0; j < 8; ++j) ones[j] = (__bf16)1.0f;

    f32x4 oacc[4][4] = {};   // [dtile][qtile]: O^T  d=quad*4+r, q=l16
    f32x4 lacc[4] = {};      // [qtile]: l per query (replicated across regs/quads)

    for (int it = 0; it < 16; ++it, kb += 16384, vb += 16384) {
#pragma unroll
        for (int g = 0; g < 2; ++g) {           // two 32-key groups per iter
            f32x4 s[2][4];
#pragma unroll
            for (int kt = 0; kt < 2; ++kt) {
                const bf16x8 k0 = *(const bf16x8*)&kb[(g * 2 + kt) * 1024 + lane * 8];
                const bf16x8 k1 = *(const bf16x8*)&kb[(g * 2 + kt) * 1024 + 512 + lane * 8];
#pragma unroll
                for (int qt = 0; qt < 4; ++qt) {
                    f32x4 a = {};
                    a = mfma32(k0, qfr[qt][0], a);
                    a = mfma32(k1, qfr[qt][1], a);
                    s[kt][qt] = a;
                }
            }
            bf16x8 pf[4];
#pragma unroll
            for (int qt = 0; qt < 4; ++qt) {
                bf16x8 pb;
#pragma unroll
                for (int kt = 0; kt < 2; ++kt)
#pragma unroll
                    for (int r = 0; r < 4; ++r)
                        pb[kt * 4 + r] = (__bf16)__builtin_amdgcn_exp2f(s[kt][qt][r]);
                pf[qt] = pb;
                lacc[qt] = mfma32(ones, pb, lacc[qt]);   // l += sum_k P
            }
#pragma unroll
            for (int dt = 0; dt < 4; ++dt) {
                const bf16x8 vfr = *(const bf16x8*)&vb[g * 2048 + dt * 512 + lane * 8];
#pragma unroll
                for (int qt = 0; qt < 4; ++qt)
                    oacc[dt][qt] = mfma32(vfr, pf[qt], oacc[dt][qt]);
            }
        }
    }

    if (quad == 0) {
#pragma unroll
        for (int qt = 0; qt < 4; ++qt) sml[w][qt * 16 + l16] = lacc[qt][0];
    }

    // two-phase 4-way wave merge (32 queries per phase to stay within LDS)
#pragma unroll
    for (int ph = 0; ph < 2; ++ph) {
        __syncthreads();
#pragma unroll
        for (int q2 = 0; q2 < 2; ++q2) {
            const int qt = ph * 2 + q2;
#pragma unroll
            for (int dt = 0; dt < 4; ++dt)
                *(f32x4*)&ldsO[w][q2 * 16 + l16][dt * 16 + quad * 4] = oacc[dt][qt];
        }
        __syncthreads();
        {
            const int q32 = tid >> 3, dseg = (tid & 7) * 8;
            const int q = ph * 32 + q32;
            const float L = sml[0][q] + sml[1][q] + sml[2][q] + sml[3][q];
            const float inv = 1.f / L;
            unsigned short o8[8];
#pragma unroll
            for (int i = 0; i < 8; ++i) {
                const float v = ldsO[0][q32][dseg + i] + ldsO[1][q32][dseg + i] +
                                ldsO[2][q32][dseg + i] + ldsO[3][q32][dseg + i];
                o8[i] = bfbits(v * inv);
            }
            *(uint4*)&attn_out[(size_t)(qb * 64 + q) * CDIM + h * DHEAD + dseg] = *(uint4*)o8;
        }
    }
}

extern "C" void kernel_launch(void* const* d_in, const int* in_sizes, int n_in,
                              void* d_out, int out_size, void* d_ws, size_t ws_size,
                              hipStream_t stream) {
    const float* x       = (const float*)d_in[0];
    const float* scale_p = (const float*)d_in[3];
    const float* Wqkv    = (const float*)d_in[4];
    const float* bqkv    = (const float*)d_in[5];
    const float* Wproj   = (const float*)d_in[6];
    const float* bproj   = (const float*)d_in[7];
    float* out = (float*)d_out;

    char* ws = (char*)d_ws;
    const size_t OFF_XB    = 0;                       // 4096*512 bf16   = 4 MB
    const size_t OFF_WQKV  = OFF_XB + 4194304;        // 1536*512 bf16   = 1.5 MB
    const size_t OFF_WPROJ = OFF_WQKV + 1572864;      // 512*512 bf16    = 0.5 MB
    const size_t OFF_QKV   = OFF_WPROJ + 524288;      // 3*4096*512 bf16 = 12 MB
    const size_t OFF_ATTN  = OFF_QKV + 12582912;      // 4096*512 bf16   = 4 MB
    const size_t NEEDED    = OFF_ATTN + 4194304;
    if (ws_size < NEEDED) return;

    unsigned short* xb     = (unsigned short*)(ws + OFF_XB);
    unsigned short* wqkvb  = (unsigned short*)(ws + OFF_WQKV);
    unsigned short* wprojb = (unsigned short*)(ws + OFF_WPROJ);
    unsigned short* qkvb   = (unsigned short*)(ws + OFF_QKV);
    unsigned short* attnb  = (unsigned short*)(ws + OFF_ATTN);

    cast3_k<<<3072, 256, 0, stream>>>(x, Wqkv, Wproj, xb, wqkvb, wprojb);

    gemm_bt<0><<<dim3(12, 64), 256, 0, stream>>>(xb, wqkvb, bqkv, scale_p,
                                                 qkvb, nullptr, NTOK, 3 * CDIM, CDIM);

    const unsigned short* qfr = qkvb;
    const unsigned short* kfr = qkvb + (size_t)PHEAD * HEADS;
    const unsigned short* vfr = qkvb + (size_t)2 * PHEAD * HEADS;
    flash3_k<<<dim3(64, 8), 256, 0, stream>>>(qfr, kfr, vfr, attnb);

    gemm_bt<1><<<dim3(4, 64), 256, 0, stream>>>(attnb, wprojb, bproj, nullptr,
                                                nullptr, out, NTOK, CDIM, CDIM);
}

// Round 5
// 159.318 us; speedup vs baseline: 1.1469x; 1.0815x over previous
//
#include <hip/hip_runtime.h>
#include <stdint.h>

#define NTOK 4096
#define CDIM 512
#define HEADS 8
#define DHEAD 64
#define PHEAD (NTOK * DHEAD)          // 262144 elems per head per tensor

typedef __bf16 bf16x8 __attribute__((ext_vector_type(8)));
typedef float f32x4 __attribute__((ext_vector_type(4)));

__device__ __forceinline__ unsigned short bfbits(float f) {
    return __builtin_bit_cast(unsigned short, (__bf16)f);   // hw v_cvt on gfx950
}

__device__ __forceinline__ f32x4 mfma32(bf16x8 a, bf16x8 b, f32x4 c) {
    return __builtin_amdgcn_mfma_f32_16x16x32_bf16(a, b, c, 0, 0, 0);
}

// ---------------- fused fp32 -> bf16 casts ----------------
__global__ void cast3_k(const float* __restrict__ x, const float* __restrict__ wq,
                        const float* __restrict__ wp,
                        unsigned short* __restrict__ xb, unsigned short* __restrict__ wqb,
                        unsigned short* __restrict__ wpb) {
    const int b = blockIdx.x;
    const float* src; unsigned short* dst; int base;
    if (b < 2048)      { src = x;  dst = xb;  base = b * 1024; }
    else if (b < 2816) { src = wq; dst = wqb; base = (b - 2048) * 1024; }
    else               { src = wp; dst = wpb; base = (b - 2816) * 1024; }
    const int i = base + threadIdx.x * 4;
    const float4 v = *(const float4*)(src + i);
    ushort4 o;
    o.x = bfbits(v.x); o.y = bfbits(v.y); o.z = bfbits(v.z); o.w = bfbits(v.w);
    *(ushort4*)(dst + i) = o;
}

// ---------------- bf16 GEMM, C = A * B^T (+bias), 64x128 tile ----------------
// MODE 0: QKV -> LDS-transposed epilogue, coalesced 16B stores into frag layouts
//         (V gets the PV-mfma32 key-permuted fragment layout)
// MODE 1: proj -> fp32 store to c_out (row-major M x Nn)
template<int MODE>
__global__ __launch_bounds__(256) void gemm_bt(
    const unsigned short* __restrict__ A,
    const unsigned short* __restrict__ Bm,
    const float* __restrict__ bias,
    const float* __restrict__ scale_p,
    unsigned short* __restrict__ qkv_out,
    float* __restrict__ c_out,
    int M, int Nn, int K)
{
    __shared__ __align__(16) unsigned short smem[64 * 136];   // 17408 B (K-loop uses 6144 elems)
    unsigned short* lA = smem;              // 64*32 elems
    unsigned short* lB = smem + 64 * 32;    // 128*32 elems

    const int tid = threadIdx.x;
    const int mBase = blockIdx.y * 64, nBase = blockIdx.x * 128;
    const int lane = tid & 63, w = tid >> 6;
    const int l16 = lane & 15, quad = lane >> 4;

    f32x4 acc[4][2] = {};   // wave w owns cols [w*32, w*32+32), all 64 rows

    for (int kt = 0; kt < K; kt += 32) {
        __syncthreads();
        {
            const int fe = tid * 8;                     // A: 2048 elems, 1 pass
            const int row = fe >> 5, col = fe & 31;
            *(uint4*)&lA[fe] = *(const uint4*)&A[(size_t)(mBase + row) * K + kt + col];
        }
#pragma unroll
        for (int i = 0; i < 2; ++i) {                   // B: 4096 elems, 2 passes
            const int fe = (i * 256 + tid) * 8;
            const int row = fe >> 5, col = fe & 31;
            *(uint4*)&lB[fe] = *(const uint4*)&Bm[(size_t)(nBase + row) * K + kt + col];
        }
        __syncthreads();

        bf16x8 af[4], bfr[2];
#pragma unroll
        for (int i = 0; i < 4; ++i)
            af[i] = *(const bf16x8*)&lA[(i * 16 + l16) * 32 + quad * 8];
#pragma unroll
        for (int j = 0; j < 2; ++j)
            bfr[j] = *(const bf16x8*)&lB[(w * 32 + j * 16 + l16) * 32 + quad * 8];
#pragma unroll
        for (int i = 0; i < 4; ++i)
#pragma unroll
            for (int j = 0; j < 2; ++j)
                acc[i][j] = mfma32(af[i], bfr[j], acc[i][j]);
    }

    if (MODE == 1) {
#pragma unroll
        for (int i = 0; i < 4; ++i)
#pragma unroll
            for (int j = 0; j < 2; ++j)
#pragma unroll
                for (int r = 0; r < 4; ++r) {
                    const int grow = mBase + i * 16 + quad * 4 + r;
                    const int gcol = nBase + w * 32 + j * 16 + l16;
                    c_out[(size_t)grow * Nn + gcol] = acc[i][j][r] + bias[gcol];
                }
    } else {
        const int three = nBase >> 9;               // block-uniform: 0 q, 1 k, 2 v
        const float scl = scale_p[0] * 1.44269504f; // fold log2(e) for exp2 softmax
        const float mul = (three == 0) ? scl : 1.0f;

        __syncthreads();   // K-loop frag reads done before overwrite
#pragma unroll
        for (int i = 0; i < 4; ++i)
#pragma unroll
            for (int j = 0; j < 2; ++j)
#pragma unroll
                for (int r = 0; r < 4; ++r) {
                    const int rl = i * 16 + quad * 4 + r;
                    const int cl = w * 32 + j * 16 + l16;
                    const float v = (acc[i][j][r] + bias[nBase + cl]) * mul;
                    smem[rl * 136 + cl] = bfbits(v);
                }
        __syncthreads();

        const size_t base3 = (size_t)three * (PHEAD * HEADS);
        if (three < 2) {
            // Q/K frag layout [h][t16][ks][quad*16+l16][8]; 16B chunk = 8 head-dims of 1 token
#pragma unroll
            for (int pass = 0; pass < 4; ++pass) {
                const int idx = pass * 256 + tid;
                const int rl16 = idx & 15, qc = (idx >> 4) & 7;
                const int hsel = (idx >> 7) & 1, t16l = (idx >> 8) & 3;
                const uint4 d = *(const uint4*)&smem[(t16l * 16 + rl16) * 136 + hsel * 64 + qc * 8];
                const int hh = ((nBase >> 6) + hsel) & 7;
                const int t16 = (mBase >> 4) + t16l;
                const size_t dst = base3 + (size_t)hh * PHEAD +
                    (size_t)(((t16 * 2 + (qc >> 2)) * 64 + (qc & 3) * 16 + rl16) * 8);
                *(uint4*)&qkv_out[dst] = d;
            }
        } else {
            // V frag layout [h][k32][dt][quad*16+l16][8]:
            // elem j = V[key = k32*32 + (j<4 ? quad*4+j : 16+quad*4+j-4)][d = dt*16+l16]
#pragma unroll
            for (int pass = 0; pass < 4; ++pass) {
                const int idx = pass * 256 + tid;
                const int l16t = idx & 15, quadt = (idx >> 4) & 3;
                const int dt = (idx >> 6) & 3, k32l = (idx >> 8) & 1, hsel = (idx >> 9) & 1;
                const int col = hsel * 64 + dt * 16 + l16t;
                unsigned short o8[8];
#pragma unroll
                for (int e = 0; e < 4; ++e) {
                    o8[e]     = smem[(k32l * 32 + quadt * 4 + e) * 136 + col];
                    o8[e + 4] = smem[(k32l * 32 + 16 + quadt * 4 + e) * 136 + col];
                }
                const int hh = ((nBase >> 6) + hsel) & 7;
                const int k32 = (mBase >> 5) + k32l;
                const size_t dst = base3 + (size_t)hh * PHEAD +
                    (size_t)(((k32 * 4 + dt) * 64 + quadt * 16 + l16t) * 8);
                *(uint4*)&qkv_out[dst] = *(uint4*)o8;
            }
        }
    }
}

// ---------------- flash attention v4: XCD-local heads + K-prefetch pipeline ----------------
// grid (8, 64): blockIdx.x = head -> linear id % 8 == head -> one head per XCD,
// K/V working set = 1 MB -> L2-resident. 4 waves split keys 4-way.
// Main loop: 32 groups of 32 keys; next group's K prefetched into ping-pong regs,
// V issued a group-body ahead of its PV use. No LDS/barriers/cross-lane in loop.
__global__ __launch_bounds__(256, 2) void flash4_k(
    const unsigned short* __restrict__ qf,
    const unsigned short* __restrict__ kf,
    const unsigned short* __restrict__ vf,
    unsigned short* __restrict__ attn_out)   // [N][C] bf16
{
    __shared__ float ldsO[4][32][68];   // [wave][q(half)][d]
    __shared__ float sml[4][64];        // per-wave l sums

    const int tid = threadIdx.x;
    const int lane = tid & 63;
    const int w = __builtin_amdgcn_readfirstlane(tid >> 6);
    const int l16 = lane & 15, quad = lane >> 4;
    const int h = blockIdx.x, qb = blockIdx.y;     // XCD swizzle: x = head

    const unsigned short* qh = qf + (size_t)h * PHEAD;
    const unsigned short* kb = kf + (size_t)h * PHEAD + w * 4096;
    const unsigned short* vb = vf + (size_t)h * PHEAD + w * 4096;

    bf16x8 qfr[4][2];
#pragma unroll
    for (int qt = 0; qt < 4; ++qt)
#pragma unroll
        for (int ks = 0; ks < 2; ++ks)
            qfr[qt][ks] = *(const bf16x8*)&qh[((qb * 4 + qt) * 2 + ks) * 512 + lane * 8];

    bf16x8 ones;
#pragma unroll
    for (int j = 0; j < 8; ++j) ones[j] = (__bf16)1.0f;

    f32x4 oacc[4][4] = {};   // [dtile][qtile]: O^T  d=quad*4+r, q=l16
    f32x4 lacc[4] = {};      // [qtile]: l per query (replicated across regs/quads)

    // group g (0..31) = 32 keys; elem offset within this wave's stream:
    //   koff(g) = (g>>1)*16384 + (g&1)*2048   (same for K and V)
#define KOFF(g) (((g) >> 1) * 16384 + ((g) & 1) * 2048)

    bf16x8 kA[4], kB[4];
#pragma unroll
    for (int i = 0; i < 4; ++i)
        kA[i] = *(const bf16x8*)&kb[KOFF(0) + i * 512 + lane * 8];

    // one group body: uses kuse (this group's K), prefetches group g+1's K into kload
    auto body = [&](int g, bf16x8* kuse, bf16x8* kload) {
        const int gn = g + 1;              // g=31 prefetch overreads into ws (safe, unused)
#pragma unroll
        for (int i = 0; i < 4; ++i)
            kload[i] = *(const bf16x8*)&kb[KOFF(gn) + i * 512 + lane * 8];
        bf16x8 vc[4];
#pragma unroll
        for (int i = 0; i < 4; ++i)
            vc[i] = *(const bf16x8*)&vb[KOFF(g) + i * 512 + lane * 8];

        f32x4 s[2][4];
#pragma unroll
        for (int kt = 0; kt < 2; ++kt)
#pragma unroll
            for (int qt = 0; qt < 4; ++qt) {
                f32x4 a = {};
                a = mfma32(kuse[kt * 2 + 0], qfr[qt][0], a);
                a = mfma32(kuse[kt * 2 + 1], qfr[qt][1], a);
                s[kt][qt] = a;
            }

        bf16x8 pf[4];
#pragma unroll
        for (int qt = 0; qt < 4; ++qt) {
            bf16x8 pb;
#pragma unroll
            for (int kt = 0; kt < 2; ++kt)
#pragma unroll
                for (int r = 0; r < 4; ++r)
                    pb[kt * 4 + r] = (__bf16)__builtin_amdgcn_exp2f(s[kt][qt][r]);
            pf[qt] = pb;
            lacc[qt] = mfma32(ones, pb, lacc[qt]);   // l += sum_k P
        }
#pragma unroll
        for (int dt = 0; dt < 4; ++dt)
#pragma unroll
            for (int qt = 0; qt < 4; ++qt)
                oacc[dt][qt] = mfma32(vc[dt], pf[qt], oacc[dt][qt]);
    };

    for (int it = 0; it < 16; ++it) {
        body(it * 2 + 0, kA, kB);
        body(it * 2 + 1, kB, kA);
    }
#undef KOFF

    if (quad == 0) {
#pragma unroll
        for (int qt = 0; qt < 4; ++qt) sml[w][qt * 16 + l16] = lacc[qt][0];
    }

    // two-phase 4-way wave merge (32 queries per phase to stay within LDS)
#pragma unroll
    for (int ph = 0; ph < 2; ++ph) {
        __syncthreads();
#pragma unroll
        for (int q2 = 0; q2 < 2; ++q2) {
            const int qt = ph * 2 + q2;
#pragma unroll
            for (int dt = 0; dt < 4; ++dt)
                *(f32x4*)&ldsO[w][q2 * 16 + l16][dt * 16 + quad * 4] = oacc[dt][qt];
        }
        __syncthreads();
        {
            const int q32 = tid >> 3, dseg = (tid & 7) * 8;
            const int q = ph * 32 + q32;
            const float L = sml[0][q] + sml[1][q] + sml[2][q] + sml[3][q];
            const float inv = 1.f / L;
            unsigned short o8[8];
#pragma unroll
            for (int i = 0; i < 8; ++i) {
                const float v = ldsO[0][q32][dseg + i] + ldsO[1][q32][dseg + i] +
                                ldsO[2][q32][dseg + i] + ldsO[3][q32][dseg + i];
                o8[i] = bfbits(v * inv);
            }
            *(uint4*)&attn_out[(size_t)(qb * 64 + q) * CDIM + h * DHEAD + dseg] = *(uint4*)o8;
        }
    }
}

extern "C" void kernel_launch(void* const* d_in, const int* in_sizes, int n_in,
                              void* d_out, int out_size, void* d_ws, size_t ws_size,
                              hipStream_t stream) {
    const float* x       = (const float*)d_in[0];
    const float* scale_p = (const float*)d_in[3];
    const float* Wqkv    = (const float*)d_in[4];
    const float* bqkv    = (const float*)d_in[5];
    const float* Wproj   = (const float*)d_in[6];
    const float* bproj   = (const float*)d_in[7];
    float* out = (float*)d_out;

    char* ws = (char*)d_ws;
    const size_t OFF_XB    = 0;                       // 4096*512 bf16   = 4 MB
    const size_t OFF_WQKV  = OFF_XB + 4194304;        // 1536*512 bf16   = 1.5 MB
    const size_t OFF_WPROJ = OFF_WQKV + 1572864;      // 512*512 bf16    = 0.5 MB
    const size_t OFF_QKV   = OFF_WPROJ + 524288;      // 3*4096*512 bf16 = 12 MB
    const size_t OFF_ATTN  = OFF_QKV + 12582912;      // 4096*512 bf16   = 4 MB
    const size_t NEEDED    = OFF_ATTN + 4194304;
    if (ws_size < NEEDED) return;

    unsigned short* xb     = (unsigned short*)(ws + OFF_XB);
    unsigned short* wqkvb  = (unsigned short*)(ws + OFF_WQKV);
    unsigned short* wprojb = (unsigned short*)(ws + OFF_WPROJ);
    unsigned short* qkvb   = (unsigned short*)(ws + OFF_QKV);
    unsigned short* attnb  = (unsigned short*)(ws + OFF_ATTN);

    cast3_k<<<3072, 256, 0, stream>>>(x, Wqkv, Wproj, xb, wqkvb, wprojb);

    gemm_bt<0><<<dim3(12, 64), 256, 0, stream>>>(xb, wqkvb, bqkv, scale_p,
                                                 qkvb, nullptr, NTOK, 3 * CDIM, CDIM);

    const unsigned short* qfr = qkvb;
    const unsigned short* kfr = qkvb + (size_t)PHEAD * HEADS;
    const unsigned short* vfr = qkvb + (size_t)2 * PHEAD * HEADS;
    flash4_k<<<dim3(8, 64), 256, 0, stream>>>(qfr, kfr, vfr, attnb);

    gemm_bt<1><<<dim3(4, 64), 256, 0, stream>>>(attnb, wprojb, bproj, nullptr,
                                                nullptr, out, NTOK, CDIM, CDIM);
}